// Round 6
// baseline (75.252 us; speedup 1.0000x reference)
//
#include <hip/hip_runtime.h>

// GrCNetConvOnly: out[b] = sum_{c,d} relu(wa[c]*h[b,d]+wb[c]*r[b,d]+wc[c]*t[b,d]+cb[c]) * fcw[c*D+d] + fcb
// B=16384, D=400, C=50.
// Packed-f16 along c (v_pk_fma_f16), f32 accumulation via v_dot2_f32_f16.
// vs R5 (64us, stall-bound): conv ds_read_b128 hoisted out of the d-loop (i-tiles, cp outer),
// conv stored as [cp][4] half2 (operands = subregisters, no extract/pack), fc stored [cp][d]
// half2 stride-1 (conflict-free, per-iter addr = base + imm), 4-entry zero pad per cp row
// makes inactive lanes (d>=400) contribute exact 0 with no masking ops.

typedef _Float16 h2 __attribute__((ext_vector_type(2)));
typedef _Float16 h8 __attribute__((ext_vector_type(8)));

constexpr int D    = 400;
constexpr int C    = 50;
constexpr int CP   = C / 2;    // 25 channel pairs
constexpr int DPAD = D + 4;    // 4 zero entries per cp row

static __device__ __forceinline__ float dot2acc(h2 a, h2 b, float c) {
#if __has_builtin(__builtin_amdgcn_fdot2)
    return __builtin_amdgcn_fdot2(a, b, c, false);
#else
    h2 p = a * b;
    return c + (float)p[0] + (float)p[1];
#endif
}

__global__ __launch_bounds__(256, 4) void grcnet_pk16b(
    const float* __restrict__ entity_emb,
    const float* __restrict__ relation_emb,
    const float* __restrict__ conv_w,       // (C,1,1,3)
    const float* __restrict__ conv_b,       // (C)
    const float* __restrict__ fc_w,         // (C*D) c-major
    const float* __restrict__ fc_b,         // (1)
    const int*   __restrict__ batch_inputs, // (B,3)
    float* __restrict__ out,                // (B)
    int nB)
{
    __shared__ h2    fc_lds[CP][DPAD];      // 40400 B, elem = {fcw[2cp,d], fcw[2cp+1,d]}
    __shared__ h2    conv_lds[CP][4];       // 400 B: [cp] = wa2, wb2, wc2, cb2
    __shared__ float partials[4][4];

    const int tid  = threadIdx.x;
    const int lane = tid & 63;
    const int wv   = tid >> 6;
    const int b0   = blockIdx.x * 16;
    if (b0 >= nB) return;

    // ---- stage fc_w (f32 c-major) -> fc_lds (h2 [cp][d]) ----
    for (int k = tid; k < CP * D; k += 256) {
        const int cp = k / D;
        const int d  = k - cp * D;
        h2 g;
        g[0] = (_Float16)fc_w[(2*cp)     * D + d];
        g[1] = (_Float16)fc_w[(2*cp + 1) * D + d];
        fc_lds[cp][d] = g;
    }
    if (tid < CP * 4) {                      // zero pad entries d=400..403
        h2 z; z[0] = (_Float16)0; z[1] = (_Float16)0;
        fc_lds[tid >> 2][D + (tid & 3)] = z;
    }
    if (tid < CP) {                          // conv params, pair-packed
        const int c0 = 2 * tid;
        h2 wa; wa[0] = (_Float16)conv_w[3*c0+0]; wa[1] = (_Float16)conv_w[3*c0+3];
        h2 wb; wb[0] = (_Float16)conv_w[3*c0+1]; wb[1] = (_Float16)conv_w[3*c0+4];
        h2 wc; wc[0] = (_Float16)conv_w[3*c0+2]; wc[1] = (_Float16)conv_w[3*c0+5];
        h2 cb; cb[0] = (_Float16)conv_b[c0];     cb[1] = (_Float16)conv_b[c0+1];
        conv_lds[tid][0] = wa; conv_lds[tid][1] = wb;
        conv_lds[tid][2] = wc; conv_lds[tid][3] = cb;
    }
    __syncthreads();

    // ---- this wave's 4 batch elements ----
    const int bbase = __builtin_amdgcn_readfirstlane(b0 + 4 * wv);
    const int* bi = batch_inputs + 3 * bbase;
    const float* eh0 = entity_emb   + (size_t)bi[0]  * D;
    const float* er0 = relation_emb + (size_t)bi[1]  * D;
    const float* et0 = entity_emb   + (size_t)bi[2]  * D;
    const float* eh1 = entity_emb   + (size_t)bi[3]  * D;
    const float* er1 = relation_emb + (size_t)bi[4]  * D;
    const float* et1 = entity_emb   + (size_t)bi[5]  * D;
    const float* eh2 = entity_emb   + (size_t)bi[6]  * D;
    const float* er2 = relation_emb + (size_t)bi[7]  * D;
    const float* et2 = entity_emb   + (size_t)bi[8]  * D;
    const float* eh3 = entity_emb   + (size_t)bi[9]  * D;
    const float* er3 = relation_emb + (size_t)bi[10] * D;
    const float* et3 = entity_emb   + (size_t)bi[11] * D;

    float acc0 = 0.f, acc1 = 0.f, acc2 = 0.f, acc3 = 0.f;
    const h2 zero2 = (h2)(_Float16)0;

    // ---- i-tiles: {0..3}, {4..6}. Within a tile: cp outer (conv hoisted), ii inner ----
    #define TILE(I0, I1)                                                          \
    {                                                                             \
        constexpr int NT = (I1) - (I0);                                           \
        h2 sh0[NT], sr0[NT], st0[NT];                                             \
        h2 sh1[NT], sr1[NT], st1[NT];                                             \
        h2 sh2[NT], sr2[NT], st2[NT];                                             \
        h2 sh3[NT], sr3[NT], st3[NT];                                             \
        int fbase[NT];                                                            \
        _Pragma("unroll")                                                         \
        for (int ii = 0; ii < NT; ++ii) {                                         \
            const int d   = lane + 64 * ((I0) + ii);                              \
            const bool a  = (d < D);                                              \
            const int dc  = a ? d : 0;       /* clamped gather index */           \
            const int dp  = a ? d : D;       /* pad index -> f2 == 0  */          \
            fbase[ii] = dp * (int)sizeof(h2);                                     \
            _Float16 v;                                                           \
            v = (_Float16)eh0[dc]; sh0[ii][0]=v; sh0[ii][1]=v;                    \
            v = (_Float16)er0[dc]; sr0[ii][0]=v; sr0[ii][1]=v;                    \
            v = (_Float16)et0[dc]; st0[ii][0]=v; st0[ii][1]=v;                    \
            v = (_Float16)eh1[dc]; sh1[ii][0]=v; sh1[ii][1]=v;                    \
            v = (_Float16)er1[dc]; sr1[ii][0]=v; sr1[ii][1]=v;                    \
            v = (_Float16)et1[dc]; st1[ii][0]=v; st1[ii][1]=v;                    \
            v = (_Float16)eh2[dc]; sh2[ii][0]=v; sh2[ii][1]=v;                    \
            v = (_Float16)er2[dc]; sr2[ii][0]=v; sr2[ii][1]=v;                    \
            v = (_Float16)et2[dc]; st2[ii][0]=v; st2[ii][1]=v;                    \
            v = (_Float16)eh3[dc]; sh3[ii][0]=v; sh3[ii][1]=v;                    \
            v = (_Float16)er3[dc]; sr3[ii][0]=v; sr3[ii][1]=v;                    \
            v = (_Float16)et3[dc]; st3[ii][0]=v; st3[ii][1]=v;                    \
        }                                                                         \
        _Pragma("unroll")                                                         \
        for (int cp = 0; cp < CP; ++cp) {                                         \
            const h8 cv = *(const h8*)&conv_lds[cp][0];   /* one b128 */          \
            const h2 wa = __builtin_shufflevector(cv, cv, 0, 1);                  \
            const h2 wb = __builtin_shufflevector(cv, cv, 2, 3);                  \
            const h2 wc = __builtin_shufflevector(cv, cv, 4, 5);                  \
            const h2 cb = __builtin_shufflevector(cv, cv, 6, 7);                  \
            _Pragma("unroll")                                                     \
            for (int ii = 0; ii < NT; ++ii) {                                     \
                const h2 f2 = *(const h2*)((const char*)&fc_lds[cp][0]            \
                                           + fbase[ii]);   /* b32, imm cp-off */  \
                h2 s0 = sh0[ii]*wa + (sr0[ii]*wb + (st0[ii]*wc + cb));            \
                h2 s1 = sh1[ii]*wa + (sr1[ii]*wb + (st1[ii]*wc + cb));            \
                h2 s2 = sh2[ii]*wa + (sr2[ii]*wb + (st2[ii]*wc + cb));            \
                h2 s3 = sh3[ii]*wa + (sr3[ii]*wb + (st3[ii]*wc + cb));            \
                s0 = __builtin_elementwise_max(s0, zero2);                        \
                s1 = __builtin_elementwise_max(s1, zero2);                        \
                s2 = __builtin_elementwise_max(s2, zero2);                        \
                s3 = __builtin_elementwise_max(s3, zero2);                        \
                acc0 = dot2acc(s0, f2, acc0);                                     \
                acc1 = dot2acc(s1, f2, acc1);                                     \
                acc2 = dot2acc(s2, f2, acc2);                                     \
                acc3 = dot2acc(s3, f2, acc3);                                     \
            }                                                                     \
        }                                                                         \
    }

    TILE(0, 4)
    TILE(4, 7)
    #undef TILE

    // ---- wave-wide sum, cross-wave via LDS ----
    #pragma unroll
    for (int off = 32; off > 0; off >>= 1) {
        acc0 += __shfl_xor(acc0, off);
        acc1 += __shfl_xor(acc1, off);
        acc2 += __shfl_xor(acc2, off);
        acc3 += __shfl_xor(acc3, off);
    }
    if (lane == 0) {
        partials[wv][0] = acc0; partials[wv][1] = acc1;
        partials[wv][2] = acc2; partials[wv][3] = acc3;
    }
    __syncthreads();

    if (tid < 16) {
        const int w = tid >> 2, j = tid & 3;
        out[b0 + 4*w + j] = partials[w][j] + fc_b[0];
    }
}

extern "C" void kernel_launch(void* const* d_in, const int* in_sizes, int n_in,
                              void* d_out, int out_size, void* d_ws, size_t ws_size,
                              hipStream_t stream) {
    const float* entity_emb   = (const float*)d_in[0];
    const float* relation_emb = (const float*)d_in[1];
    const float* conv_w       = (const float*)d_in[2];
    const float* conv_b       = (const float*)d_in[3];
    const float* fc_w         = (const float*)d_in[4];
    const float* fc_b         = (const float*)d_in[5];
    const int*   batch_inputs = (const int*)d_in[6];
    float* out = (float*)d_out;

    const int nB = in_sizes[6] / 3;          // 16384
    const int blocks = (nB + 15) / 16;       // 1024
    grcnet_pk16b<<<blocks, 256, 0, stream>>>(
        entity_emb, relation_emb, conv_w, conv_b, fc_w, fc_b, batch_inputs, out, nB);
}

// Round 7
// 49.478 us; speedup vs baseline: 1.5209x; 1.5209x over previous
//
#include <hip/hip_runtime.h>

// GrCNetConvOnly: out[b] = sum_{c,d} relu(wa[c]*h[b,d]+wb[c]*r[b,d]+wc[c]*t[b,d]+cb[c]) * fcw[c*D+d] + fcb
// B=16384, D=400, C=50.
// Packed-f16 along c (v_pk_fma_f16) + f32 accumulate (v_dot2_f32_f16).
// R6 failed on hipcc's 64-VGPR occupancy squeeze (96MB scratch): fix with
// amdgpu_waves_per_eu(2,4) (VGPR cap 128-256) + cp-split across wave pairs so conv
// params live in ~52 registers for the whole kernel. Inner loop per (i,cp):
// 1 ds_read_b32 (fc, compile-time offset) + 12 pkfma + 4 pkmax + 4 dot2 for 8 elements.
// #pragma unroll 1 on the i-loop keeps only 12 gather values live at a time.

typedef _Float16 h2 __attribute__((ext_vector_type(2)));

constexpr int D    = 400;
constexpr int C    = 50;
constexpr int CP   = C / 2;    // 25 channel pairs
constexpr int DPAD = D + 4;    // 4 zeroed pad entries -> inactive lanes contribute 0

static __device__ __forceinline__ float dot2acc(h2 a, h2 b, float c) {
#if __has_builtin(__builtin_amdgcn_fdot2)
    return __builtin_amdgcn_fdot2(a, b, c, false);
#else
    h2 p = a * b;
    return c + (float)p[0] + (float)p[1];
#endif
}

__global__ __attribute__((amdgpu_flat_work_group_size(512, 512), amdgpu_waves_per_eu(2, 4)))
void grcnet_pk16c(
    const float* __restrict__ entity_emb,
    const float* __restrict__ relation_emb,
    const float* __restrict__ conv_w,       // (C,1,1,3)
    const float* __restrict__ conv_b,       // (C)
    const float* __restrict__ fc_w,         // (C*D) c-major
    const float* __restrict__ fc_b,         // (1)
    const int*   __restrict__ batch_inputs, // (B,3)
    float* __restrict__ out,                // (B)
    int nB)
{
    __shared__ h2    fc_lds[CP][DPAD];      // 40400 B; elem = {fcw[2cp,d], fcw[2cp+1,d]}
    __shared__ h2    conv_lds[CP][4];       // [cp] = wa2, wb2, wc2, cb2 (16 B each)
    __shared__ float partials[2][4][4];     // [cp-half][b-group][b]

    const int tid  = threadIdx.x;
    const int lane = tid & 63;
    const int wv   = tid >> 6;              // 0..7
    const int grp  = wv >> 1;               // b-group 0..3
    const int hc   = wv & 1;                // cp-half 0..1
    const int b0   = blockIdx.x * 16;
    if (b0 >= nB) return;

    // ---- stage fc_w (f32 c-major) -> fc_lds (h2 [cp][d]) ----
    for (int k = tid; k < CP * D; k += 512) {
        const int cp = k / D;
        const int d  = k - cp * D;
        h2 g;
        g[0] = (_Float16)fc_w[(2*cp)     * D + d];
        g[1] = (_Float16)fc_w[(2*cp + 1) * D + d];
        fc_lds[cp][d] = g;
    }
    if (tid < CP * 4) {                      // zero pad entries d=400..403
        h2 z; z[0] = (_Float16)0; z[1] = (_Float16)0;
        fc_lds[tid >> 2][D + (tid & 3)] = z;
    }
    if (tid < CP) {                          // conv params, pair-packed
        const int c0 = 2 * tid;
        h2 wa; wa[0] = (_Float16)conv_w[3*c0+0]; wa[1] = (_Float16)conv_w[3*c0+3];
        h2 wb; wb[0] = (_Float16)conv_w[3*c0+1]; wb[1] = (_Float16)conv_w[3*c0+4];
        h2 wc; wc[0] = (_Float16)conv_w[3*c0+2]; wc[1] = (_Float16)conv_w[3*c0+5];
        h2 cb; cb[0] = (_Float16)conv_b[c0];     cb[1] = (_Float16)conv_b[c0+1];
        conv_lds[tid][0] = wa; conv_lds[tid][1] = wb;
        conv_lds[tid][2] = wc; conv_lds[tid][3] = cb;
    }
    __syncthreads();

    // ---- this wave's 4 batch elements ----
    const int bbase = __builtin_amdgcn_readfirstlane(b0 + 4 * grp);
    const int* bi = batch_inputs + 3 * bbase;
    const float* eh0 = entity_emb   + (size_t)bi[0]  * D;
    const float* er0 = relation_emb + (size_t)bi[1]  * D;
    const float* et0 = entity_emb   + (size_t)bi[2]  * D;
    const float* eh1 = entity_emb   + (size_t)bi[3]  * D;
    const float* er1 = relation_emb + (size_t)bi[4]  * D;
    const float* et1 = entity_emb   + (size_t)bi[5]  * D;
    const float* eh2 = entity_emb   + (size_t)bi[6]  * D;
    const float* er2 = relation_emb + (size_t)bi[7]  * D;
    const float* et2 = entity_emb   + (size_t)bi[8]  * D;
    const float* eh3 = entity_emb   + (size_t)bi[9]  * D;
    const float* er3 = relation_emb + (size_t)bi[10] * D;
    const float* et3 = entity_emb   + (size_t)bi[11] * D;

    float acc0 = 0.f, acc1 = 0.f, acc2 = 0.f, acc3 = 0.f;
    const h2 zero2 = (h2)(_Float16)0;

    // BODY(C0, C1): conv hoisted to registers for [C0,C1), i-loop NOT unrolled
    // (12 live gather values), cp-loop fully unrolled (f2 addr = base + imm).
    #define BODY(C0, C1)                                                          \
    {                                                                             \
        constexpr int NC = (C1) - (C0);                                           \
        h2 cwa[NC], cwb[NC], cwcv[NC], ccb[NC];                                   \
        _Pragma("unroll")                                                         \
        for (int j = 0; j < NC; ++j) {                                            \
            cwa[j]  = conv_lds[(C0) + j][0];                                      \
            cwb[j]  = conv_lds[(C0) + j][1];                                      \
            cwcv[j] = conv_lds[(C0) + j][2];                                      \
            ccb[j]  = conv_lds[(C0) + j][3];                                      \
        }                                                                         \
        _Pragma("unroll 1")                                                       \
        for (int i = 0; i < 7; ++i) {                                             \
            const int d  = lane + 64 * i;                                         \
            const bool a = (d < D);                                               \
            const int dc = a ? d : 0;        /* clamped gather index */           \
            const int dp = a ? d : D;        /* pad index -> f2 == 0 */           \
            const char* fcol = (const char*)&fc_lds[C0][dp];                      \
            _Float16 v;                                                           \
            h2 h0, r0, t0, h1, r1, t1, h2_, r2, t2, h3, r3, t3;                   \
            v = (_Float16)eh0[dc]; h0[0]=v;  h0[1]=v;                             \
            v = (_Float16)er0[dc]; r0[0]=v;  r0[1]=v;                             \
            v = (_Float16)et0[dc]; t0[0]=v;  t0[1]=v;                             \
            v = (_Float16)eh1[dc]; h1[0]=v;  h1[1]=v;                             \
            v = (_Float16)er1[dc]; r1[0]=v;  r1[1]=v;                             \
            v = (_Float16)et1[dc]; t1[0]=v;  t1[1]=v;                             \
            v = (_Float16)eh2[dc]; h2_[0]=v; h2_[1]=v;                            \
            v = (_Float16)er2[dc]; r2[0]=v;  r2[1]=v;                             \
            v = (_Float16)et2[dc]; t2[0]=v;  t2[1]=v;                             \
            v = (_Float16)eh3[dc]; h3[0]=v;  h3[1]=v;                             \
            v = (_Float16)er3[dc]; r3[0]=v;  r3[1]=v;                             \
            v = (_Float16)et3[dc]; t3[0]=v;  t3[1]=v;                             \
            _Pragma("unroll")                                                     \
            for (int j = 0; j < NC; ++j) {                                        \
                const h2 f2 = *(const h2*)(fcol + (size_t)(j * (DPAD * 4)));      \
                h2 s0 = h0 *cwa[j] + (r0*cwb[j] + (t0*cwcv[j] + ccb[j]));         \
                h2 s1 = h1 *cwa[j] + (r1*cwb[j] + (t1*cwcv[j] + ccb[j]));         \
                h2 s2 = h2_*cwa[j] + (r2*cwb[j] + (t2*cwcv[j] + ccb[j]));         \
                h2 s3 = h3 *cwa[j] + (r3*cwb[j] + (t3*cwcv[j] + ccb[j]));         \
                s0 = __builtin_elementwise_max(s0, zero2);                        \
                s1 = __builtin_elementwise_max(s1, zero2);                        \
                s2 = __builtin_elementwise_max(s2, zero2);                        \
                s3 = __builtin_elementwise_max(s3, zero2);                        \
                acc0 = dot2acc(s0, f2, acc0);                                     \
                acc1 = dot2acc(s1, f2, acc1);                                     \
                acc2 = dot2acc(s2, f2, acc2);                                     \
                acc3 = dot2acc(s3, f2, acc3);                                     \
            }                                                                     \
        }                                                                         \
    }

    if (hc == 0) { BODY(0, 13) } else { BODY(13, 25) }
    #undef BODY

    // ---- wave-wide sum, cross-wave via LDS ----
    #pragma unroll
    for (int off = 32; off > 0; off >>= 1) {
        acc0 += __shfl_xor(acc0, off);
        acc1 += __shfl_xor(acc1, off);
        acc2 += __shfl_xor(acc2, off);
        acc3 += __shfl_xor(acc3, off);
    }
    if (lane == 0) {
        partials[hc][grp][0] = acc0; partials[hc][grp][1] = acc1;
        partials[hc][grp][2] = acc2; partials[hc][grp][3] = acc3;
    }
    __syncthreads();

    if (tid < 16) {
        const int g = tid >> 2, j = tid & 3;
        out[b0 + 4*g + j] = partials[0][g][j] + partials[1][g][j] + fc_b[0];
    }
}

extern "C" void kernel_launch(void* const* d_in, const int* in_sizes, int n_in,
                              void* d_out, int out_size, void* d_ws, size_t ws_size,
                              hipStream_t stream) {
    const float* entity_emb   = (const float*)d_in[0];
    const float* relation_emb = (const float*)d_in[1];
    const float* conv_w       = (const float*)d_in[2];
    const float* conv_b       = (const float*)d_in[3];
    const float* fc_w         = (const float*)d_in[4];
    const float* fc_b         = (const float*)d_in[5];
    const int*   batch_inputs = (const int*)d_in[6];
    float* out = (float*)d_out;

    const int nB = in_sizes[6] / 3;          // 16384
    const int blocks = (nB + 15) / 16;       // 1024
    grcnet_pk16c<<<blocks, 512, 0, stream>>>(
        entity_emb, relation_emb, conv_w, conv_b, fc_w, fc_b, batch_inputs, out, nB);
}

// Round 8
// 45.731 us; speedup vs baseline: 1.6455x; 1.0819x over previous
//
#include <hip/hip_runtime.h>

// GrCNetConvOnly: out[b] = sum_{c,d} relu(wa[c]*h[b,d]+wb[c]*r[b,d]+wc[c]*t[b,d]+cb[c]) * fcw[c*D+d] + fcb
// B=16384, D=400, C=50.
// R7 (49.5us) = cp-split pk16, but unroll-1 i-loop serialized HBM gather latency (~900cy,
// L3 evicted by harness poison fills) and paid 64-bit addr math per load.
// R8: explicit 2-slot software pipeline (LOAD next || COMPUTE current), all gather+fc
// addresses = base + compile-time immediate (slots 0..5 have no inactive lanes since
// max d = 383 < 400; only slot 6 clamps). fc staged via float4 -> b128 ds_write.

typedef _Float16 h2 __attribute__((ext_vector_type(2)));
typedef _Float16 h8 __attribute__((ext_vector_type(8)));

constexpr int D    = 400;
constexpr int CP   = 25;     // channel pairs
constexpr int DPAD = 404;    // 4 zeroed pad entries: inactive lanes read f2 = 0

static __device__ __forceinline__ float dot2acc(h2 a, h2 b, float c) {
#if __has_builtin(__builtin_amdgcn_fdot2)
    return __builtin_amdgcn_fdot2(a, b, c, false);
#else
    h2 p = a * b; return c + (float)p[0] + (float)p[1];
#endif
}
static __device__ __forceinline__ h2 dup(float v) {
    _Float16 x = (_Float16)v; h2 r; r[0] = x; r[1] = x; return r;
}

__global__ __attribute__((amdgpu_flat_work_group_size(512, 512), amdgpu_waves_per_eu(2, 4)))
void grcnet_pk16d(
    const float* __restrict__ entity_emb,
    const float* __restrict__ relation_emb,
    const float* __restrict__ conv_w,       // (C,1,1,3)
    const float* __restrict__ conv_b,       // (C)
    const float* __restrict__ fc_w,         // (C*D) c-major
    const float* __restrict__ fc_b,         // (1)
    const int*   __restrict__ batch_inputs, // (B,3)
    float* __restrict__ out,                // (B)
    int nB)
{
    __shared__ h2    fc_lds[CP][DPAD];      // 40400 B; elem = {fcw[2cp,d], fcw[2cp+1,d]}
    __shared__ h2    conv_lds[CP][4];       // [cp] = wa2, wb2, wc2, cb2
    __shared__ float partials[2][4][4];

    const int tid  = threadIdx.x;
    const int lane = tid & 63;
    const int wv   = tid >> 6;              // 0..7
    const int grp  = wv >> 1;               // b-group 0..3
    const int hc   = wv & 1;                // cp-half 0..1
    const int b0   = blockIdx.x * 16;
    if (b0 >= nB) return;

    // ---- stage fc_w: float4 x2 -> one b128 ds_write (2500 quad-items) ----
    for (int k = tid; k < CP * 100; k += 512) {
        const int cp = k / 100;
        const int dq = k - cp * 100;
        const float4 A  = *(const float4*)(fc_w + (2*cp)     * D + 4*dq);
        const float4 Bv = *(const float4*)(fc_w + (2*cp + 1) * D + 4*dq);
        h8 g;
        g[0]=(_Float16)A.x; g[1]=(_Float16)Bv.x;
        g[2]=(_Float16)A.y; g[3]=(_Float16)Bv.y;
        g[4]=(_Float16)A.z; g[5]=(_Float16)Bv.z;
        g[6]=(_Float16)A.w; g[7]=(_Float16)Bv.w;
        *(h8*)&fc_lds[cp][4*dq] = g;
    }
    if (tid < CP * 4) {                      // zero pad d=400..403
        h2 z; z[0] = (_Float16)0; z[1] = (_Float16)0;
        fc_lds[tid >> 2][D + (tid & 3)] = z;
    }
    if (tid < CP) {                          // conv params, pair-packed
        const int c0 = 2 * tid;
        h2 wa, wb, wc, cb;
        wa[0]=(_Float16)conv_w[3*c0+0]; wa[1]=(_Float16)conv_w[3*c0+3];
        wb[0]=(_Float16)conv_w[3*c0+1]; wb[1]=(_Float16)conv_w[3*c0+4];
        wc[0]=(_Float16)conv_w[3*c0+2]; wc[1]=(_Float16)conv_w[3*c0+5];
        cb[0]=(_Float16)conv_b[c0];     cb[1]=(_Float16)conv_b[c0+1];
        conv_lds[tid][0]=wa; conv_lds[tid][1]=wb;
        conv_lds[tid][2]=wc; conv_lds[tid][3]=cb;
    }
    __syncthreads();

    // ---- this wave's 4 batch elements; base pointers pre-offset by lane ----
    const int bbase = __builtin_amdgcn_readfirstlane(b0 + 4 * grp);
    const int* bi = batch_inputs + 3 * bbase;
    const float* p0h = entity_emb   + (size_t)bi[0]  * D + lane;
    const float* p0r = relation_emb + (size_t)bi[1]  * D + lane;
    const float* p0t = entity_emb   + (size_t)bi[2]  * D + lane;
    const float* p1h = entity_emb   + (size_t)bi[3]  * D + lane;
    const float* p1r = relation_emb + (size_t)bi[4]  * D + lane;
    const float* p1t = entity_emb   + (size_t)bi[5]  * D + lane;
    const float* p2h = entity_emb   + (size_t)bi[6]  * D + lane;
    const float* p2r = relation_emb + (size_t)bi[7]  * D + lane;
    const float* p2t = entity_emb   + (size_t)bi[8]  * D + lane;
    const float* p3h = entity_emb   + (size_t)bi[9]  * D + lane;
    const float* p3r = relation_emb + (size_t)bi[10] * D + lane;
    const float* p3t = entity_emb   + (size_t)bi[11] * D + lane;

    // slot 6 (d = lane+384): clamp inactive lanes to row start; fc reads pad row (=0)
    const int  d6  = lane + 384;
    const bool a6  = (d6 < D);
    const int  i6  = a6 ? 384 : -lane;       // p[i6] == row[dc6]
    const h2*  fcb  = (const h2*)fc_lds + lane;          // slots 0..5 fc base
    const h2*  fcb6 = (const h2*)fc_lds + (a6 ? d6 : D); // slot 6 fc base

    float acc0 = 0.f, acc1 = 0.f, acc2 = 0.f, acc3 = 0.f;
    const h2 zero2 = (h2)(_Float16)0;

    #define LOADI(S, IDX)                                                         \
        f##S##_0h = p0h[IDX]; f##S##_0r = p0r[IDX]; f##S##_0t = p0t[IDX];         \
        f##S##_1h = p1h[IDX]; f##S##_1r = p1r[IDX]; f##S##_1t = p1t[IDX];         \
        f##S##_2h = p2h[IDX]; f##S##_2r = p2r[IDX]; f##S##_2t = p2t[IDX];         \
        f##S##_3h = p3h[IDX]; f##S##_3r = p3r[IDX]; f##S##_3t = p3t[IDX];

    #define COMPUTE(S, FB, FIDX0)                                                 \
    {                                                                             \
        const h2 H0 = dup(f##S##_0h), R0 = dup(f##S##_0r), T0 = dup(f##S##_0t);   \
        const h2 H1 = dup(f##S##_1h), R1 = dup(f##S##_1r), T1 = dup(f##S##_1t);   \
        const h2 H2 = dup(f##S##_2h), R2 = dup(f##S##_2r), T2 = dup(f##S##_2t);   \
        const h2 H3 = dup(f##S##_3h), R3 = dup(f##S##_3r), T3 = dup(f##S##_3t);   \
        _Pragma("unroll")                                                         \
        for (int j = 0; j < NC; ++j) {                                            \
            const h2 f2 = (FB)[(FIDX0) + (C0 + j) * DPAD];  /* imm offset */      \
            h2 s0 = H0*cwa[j] + (R0*cwb[j] + (T0*cwc[j] + ccb[j]));               \
            h2 s1 = H1*cwa[j] + (R1*cwb[j] + (T1*cwc[j] + ccb[j]));               \
            h2 s2 = H2*cwa[j] + (R2*cwb[j] + (T2*cwc[j] + ccb[j]));               \
            h2 s3 = H3*cwa[j] + (R3*cwb[j] + (T3*cwc[j] + ccb[j]));               \
            s0 = __builtin_elementwise_max(s0, zero2);                            \
            s1 = __builtin_elementwise_max(s1, zero2);                            \
            s2 = __builtin_elementwise_max(s2, zero2);                            \
            s3 = __builtin_elementwise_max(s3, zero2);                            \
            acc0 = dot2acc(s0, f2, acc0);                                         \
            acc1 = dot2acc(s1, f2, acc1);                                         \
            acc2 = dot2acc(s2, f2, acc2);                                         \
            acc3 = dot2acc(s3, f2, acc3);                                         \
        }                                                                         \
    }

    #define BODY(C0_, NC_)                                                        \
    {                                                                             \
        constexpr int C0 = (C0_), NC = (NC_);                                     \
        h2 cwa[NC], cwb[NC], cwc[NC], ccb[NC];                                    \
        _Pragma("unroll")                                                         \
        for (int j = 0; j < NC; ++j) {                                            \
            cwa[j] = conv_lds[C0+j][0]; cwb[j] = conv_lds[C0+j][1];               \
            cwc[j] = conv_lds[C0+j][2]; ccb[j] = conv_lds[C0+j][3];               \
        }                                                                         \
        float fA_0h, fA_0r, fA_0t, fA_1h, fA_1r, fA_1t;                           \
        float fA_2h, fA_2r, fA_2t, fA_3h, fA_3r, fA_3t;                           \
        float fB_0h, fB_0r, fB_0t, fB_1h, fB_1r, fB_1t;                           \
        float fB_2h, fB_2r, fB_2t, fB_3h, fB_3r, fB_3t;                           \
        LOADI(A, 0)                                                               \
        LOADI(B, 64)   COMPUTE(A, fcb, 0*64)                                      \
        LOADI(A, 128)  COMPUTE(B, fcb, 1*64)                                      \
        LOADI(B, 192)  COMPUTE(A, fcb, 2*64)                                      \
        LOADI(A, 256)  COMPUTE(B, fcb, 3*64)                                      \
        LOADI(B, 320)  COMPUTE(A, fcb, 4*64)                                      \
        LOADI(A, i6)   COMPUTE(B, fcb, 5*64)                                      \
                       COMPUTE(A, fcb6, 0)                                        \
    }

    if (hc == 0) { BODY(0, 13) } else { BODY(13, 12) }
    #undef BODY
    #undef COMPUTE
    #undef LOADI

    // ---- wave-wide sum, cross-wave via LDS ----
    #pragma unroll
    for (int off = 32; off > 0; off >>= 1) {
        acc0 += __shfl_xor(acc0, off);
        acc1 += __shfl_xor(acc1, off);
        acc2 += __shfl_xor(acc2, off);
        acc3 += __shfl_xor(acc3, off);
    }
    if (lane == 0) {
        partials[hc][grp][0] = acc0; partials[hc][grp][1] = acc1;
        partials[hc][grp][2] = acc2; partials[hc][grp][3] = acc3;
    }
    __syncthreads();

    if (tid < 16) {
        const int g = tid >> 2, j = tid & 3;
        out[b0 + 4*g + j] = partials[0][g][j] + partials[1][g][j] + fc_b[0];
    }
}

extern "C" void kernel_launch(void* const* d_in, const int* in_sizes, int n_in,
                              void* d_out, int out_size, void* d_ws, size_t ws_size,
                              hipStream_t stream) {
    const float* entity_emb   = (const float*)d_in[0];
    const float* relation_emb = (const float*)d_in[1];
    const float* conv_w       = (const float*)d_in[2];
    const float* conv_b       = (const float*)d_in[3];
    const float* fc_w         = (const float*)d_in[4];
    const float* fc_b         = (const float*)d_in[5];
    const int*   batch_inputs = (const int*)d_in[6];
    float* out = (float*)d_out;

    const int nB = in_sizes[6] / 3;          // 16384
    const int blocks = (nB + 15) / 16;       // 1024
    grcnet_pk16d<<<blocks, 512, 0, stream>>>(
        entity_emb, relation_emb, conv_w, conv_b, fc_w, fc_b, batch_inputs, out, nB);
}